// Round 3
// baseline (391.325 us; speedup 1.0000x reference)
//
#include <hip/hip_runtime.h>
#include <hip/hip_bf16.h>
#include <stdint.h>

#define M_POS 0.5f
#define M_NEG 0.1f
#define LAM_NEG 1.0f

typedef __attribute__((ext_vector_type(8))) short short8;   // 8 bf16 = 4 VGPRs
typedef __attribute__((ext_vector_type(4))) float floatx4;  // MFMA accumulator

// ---------------- Kernel A: row sumsq, inv_norm, fp32 -> bf16 cast, zero accumulators ----
// One wave per row (4 rows/block). Also zeroes pos_acc/neg_acc/counter (replaces memset).
__global__ __launch_bounds__(256) void prep_kernel(
    const float* __restrict__ cb, __hip_bfloat16* __restrict__ cb_bf,
    float* __restrict__ sq, float* __restrict__ inv_norm,
    unsigned* __restrict__ zero_base, int zero_len,   // pos/neg acc + counter, as u32
    int N, int d)
{
    const int gi = blockIdx.x * 256 + threadIdx.x;
    if (gi < zero_len) zero_base[gi] = 0u;

    const int wave = threadIdx.x >> 6;
    const int lane = threadIdx.x & 63;
    const int row = blockIdx.x * 4 + wave;
    if (row >= N) return;
    const float* src = cb + (size_t)row * d;
    __hip_bfloat16* dst = cb_bf + (size_t)row * d;

    float s = 0.f;
    for (int c = lane * 4; c < d; c += 256) {
        float4 v = *(const float4*)(src + c);
        s += v.x * v.x + v.y * v.y + v.z * v.z + v.w * v.w;
        __hip_bfloat16 h[4];
        h[0] = __float2bfloat16(v.x);
        h[1] = __float2bfloat16(v.y);
        h[2] = __float2bfloat16(v.z);
        h[3] = __float2bfloat16(v.w);
        *(uint2*)(dst + c) = *(uint2*)h;
    }
    for (int o = 32; o > 0; o >>= 1) s += __shfl_down(s, o, 64);
    if (lane == 0) {
        sq[row] = s;
        inv_norm[row] = rsqrtf(s);
    }
}

// ---------------- Kernel B: fused symmetric Gram GEMM + loss epilogue + finalize ----------
// Upper-triangular 128x128 tiles (by <= bx); off-diag tiles contribute each (i,j) to both
// row i and row j. XOR-swizzled LDS (0 bank conflicts, verified R2). Epilogue takes a
// wave-uniform fast path (nterm only) when no row/col of the wave's window can have a
// positive pair — true for ~97% of tiles with 64-aligned groups. Last block finalizes.
__global__ __launch_bounds__(256) void gram_loss_kernel(
    const __hip_bfloat16* __restrict__ A,   // N x d bf16
    const float* __restrict__ sq, const float* __restrict__ inv_norm,
    const int* __restrict__ starts, const int* __restrict__ ends,
    const int* __restrict__ max_ip,
    float* __restrict__ pos_acc, float* __restrict__ neg_acc,
    unsigned* __restrict__ counter, float* __restrict__ out,
    int N, int d)
{
    const int M = min(N, max_ip[0] + 1);

    // triangular decode: blockIdx.x -> (by, bx), by <= bx
    const int t = blockIdx.x;
    int bx = (int)((sqrtf(8.f * (float)t + 1.f) - 1.f) * 0.5f);
    while ((bx + 1) * (bx + 2) / 2 <= t) bx++;
    while (bx * (bx + 1) / 2 > t) bx--;
    const int by = t - bx * (bx + 1) / 2;

    const int rowBase = by * 128;
    const int colBase = bx * 128;
    const bool isDiag = (by == bx);

    __shared__ __hip_bfloat16 ldsA[128 * 64];
    __shared__ __hip_bfloat16 ldsB[128 * 64];

    const int tid  = threadIdx.x;
    const int wave = tid >> 6;
    const int lane = tid & 63;
    const int wr = (wave >> 1) * 64;
    const int wc = (wave & 1) * 64;

    floatx4 acc[4][4];
#pragma unroll
    for (int a = 0; a < 4; ++a)
#pragma unroll
        for (int b = 0; b < 4; ++b) acc[a][b] = (floatx4){0.f, 0.f, 0.f, 0.f};

    const int ldRow = lane >> 3;
    const int dstCol = (lane & 7) * 8;
    const int srcCol = ((lane ^ ldRow) & 7) * 8;
    const int kTiles = d / 64;

    for (int kt = 0; kt < kTiles; ++kt) {
        __syncthreads();
        const int k0 = kt * 64;
#pragma unroll
        for (int q = 0; q < 4; ++q) {
            const int r = q * 32 + wave * 8 + ldRow;
            const __hip_bfloat16* ga = A + (size_t)(rowBase + r) * d + k0 + srcCol;
            const __hip_bfloat16* gb = A + (size_t)(colBase + r) * d + k0 + srcCol;
            __builtin_amdgcn_global_load_lds(
                (const __attribute__((address_space(1))) void*)ga,
                (__attribute__((address_space(3))) void*)(ldsA + r * 64 + dstCol), 16, 0, 0);
            __builtin_amdgcn_global_load_lds(
                (const __attribute__((address_space(1))) void*)gb,
                (__attribute__((address_space(3))) void*)(ldsB + r * 64 + dstCol), 16, 0, 0);
        }
        __syncthreads();

        const int rl = lane & 15;
        const int g  = lane >> 4;
#pragma unroll
        for (int ko = 0; ko < 2; ++ko) {
            const int kc = ko * 4 + g;
            short8 af[4], bf[4];
#pragma unroll
            for (int t4 = 0; t4 < 4; ++t4) {
                const int ra = wr + t4 * 16 + rl;
                const int rb = wc + t4 * 16 + rl;
                af[t4] = *(const short8*)(ldsA + ra * 64 + ((kc ^ (rl & 7)) * 8));
                bf[t4] = *(const short8*)(ldsB + rb * 64 + ((kc ^ (rl & 7)) * 8));
            }
#pragma unroll
            for (int rt = 0; rt < 4; ++rt)
#pragma unroll
                for (int ct = 0; ct < 4; ++ct)
                    acc[rt][ct] = __builtin_amdgcn_mfma_f32_16x16x32_bf16(
                        af[rt], bf[ct], acc[rt][ct], 0, 0, 0);
        }
    }

    // ---- epilogue ----
    const int rl = lane & 15;
    const int q  = lane >> 4;
    const int jlo = colBase + wc;         // wave's j-window [jlo, jlo+63]
    const int ilo = rowBase + wr;         // wave's i-window [ilo, ilo+63]

    int   jn[4], jns[4], jne[4];
    float jsq[4], jinv[4];
    bool  jvalid[4];
#pragma unroll
    for (int ct = 0; ct < 4; ++ct) {
        const int j = colBase + wc + ct * 16 + rl;
        jn[ct]  = j;
        jsq[ct] = sq[j];
        jinv[ct] = inv_norm[j];
        jvalid[ct] = (j < M);
        jns[ct] = jvalid[ct] ? starts[j] : 0;
        jne[ct] = jvalid[ct] ? ends[j]   : -1;
    }

    // can any column of this wave have a positive pair against the wave's i-window?
    bool colPosLane = false;
    if (!isDiag) {
#pragma unroll
        for (int ct = 0; ct < 4; ++ct)
            colPosLane |= jvalid[ct] && (jne[ct] >= ilo) && (jns[ct] <= ilo + 63);
    }
    const bool anyColPos = (__ballot(colPosLane) != 0ULL);

    float posc[4] = {0.f, 0.f, 0.f, 0.f};
    float negc[4] = {0.f, 0.f, 0.f, 0.f};

#pragma unroll
    for (int rt = 0; rt < 4; ++rt) {
        const int ibase = rowBase + wr + rt * 16 + q * 4;
#pragma unroll
        for (int reg = 0; reg < 4; ++reg) {
            const int i = ibase + reg;
            const bool rowValid = (i < M);
            const int ns = rowValid ? starts[i] : 0;
            const int ne = rowValid ? ends[i]   : -1;
            const float iinv = inv_norm[i];
            const bool rowHasPos = rowValid && (ne >= jlo) && (ns <= jlo + 63);
            const bool fullPath = (__ballot(rowHasPos) != 0ULL) || anyColPos;

            float posp = 0.f, negp = 0.f;
            if (fullPath) {
                const float isq = sq[i];
#pragma unroll
                for (int ct = 0; ct < 4; ++ct) {
                    const float dot = acc[rt][ct][reg];
                    const int j = jn[ct];
                    float cosv = dot * iinv * jinv[ct];
                    cosv = fminf(fmaxf(cosv, -1.f), 1.f);
                    float tn = fmaxf(fabsf(cosv) - M_NEG, 0.f);
                    const float nterm = tn * tn;
                    const float d2 = fmaxf(isq + jsq[ct] - 2.f * dot, 0.f);
                    float tp = fmaxf(sqrtf(d2) - M_POS, 0.f);
                    const float pterm = tp * tp;
                    const bool dg = (j == i);
                    if (rowValid) {
                        const bool in_r = (j >= ns) && (j <= ne);
                        if (in_r && !dg) posp += pterm;
                        if (!in_r || dg) negp += nterm;
                    }
                    if (!isDiag && jvalid[ct]) {
                        const bool in_c = (i >= jns[ct]) && (i <= jne[ct]);
                        if (in_c && !dg) posc[ct] += pterm;
                        if (!in_c || dg) negc[ct] += nterm;
                    }
                }
            } else {
                // no positive pair possible in this wave for row or col side:
                // neg mask is unconditionally true everywhere (incl. diagonal)
#pragma unroll
                for (int ct = 0; ct < 4; ++ct) {
                    const float dot = acc[rt][ct][reg];
                    float cosv = dot * iinv * jinv[ct];
                    cosv = fminf(fmaxf(cosv, -1.f), 1.f);
                    float tn = fmaxf(fabsf(cosv) - M_NEG, 0.f);
                    const float nterm = tn * tn;
                    negp += nterm;                       // unused if !rowValid (atomic gated)
                    if (!isDiag && jvalid[ct]) negc[ct] += nterm;
                }
            }
            // reduce over the 16 column-lanes of this row (xor 1,2,4,8 stays within q-group)
#pragma unroll
            for (int m = 1; m < 16; m <<= 1) {
                posp += __shfl_xor(posp, m, 64);
                negp += __shfl_xor(negp, m, 64);
            }
            if (rowValid && rl == 0) {
                atomicAdd(&pos_acc[i], posp);
                atomicAdd(&neg_acc[i], negp);
            }
        }
    }

    if (!isDiag) {
#pragma unroll
        for (int ct = 0; ct < 4; ++ct) {
            posc[ct] += __shfl_xor(posc[ct], 16, 64);
            posc[ct] += __shfl_xor(posc[ct], 32, 64);
            negc[ct] += __shfl_xor(negc[ct], 16, 64);
            negc[ct] += __shfl_xor(negc[ct], 32, 64);
        }
        if (q == 0) {
#pragma unroll
            for (int ct = 0; ct < 4; ++ct) {
                if (jvalid[ct]) {
                    atomicAdd(&pos_acc[jn[ct]], posc[ct]);
                    atomicAdd(&neg_acc[jn[ct]], negc[ct]);
                }
            }
        }
    }

    // ---- last-block finalize ----
    __shared__ bool amLast;
    __threadfence();
    if (tid == 0) {
        unsigned old = atomicAdd(counter, 1u);
        amLast = (old == gridDim.x - 1);
    }
    __syncthreads();
    if (amLast) {
        __threadfence();
        float total = 0.f;
        int cnt = 0;
        for (int i = tid; i < M; i += 256) {
            const float pa = __hip_atomic_load(&pos_acc[i], __ATOMIC_RELAXED, __HIP_MEMORY_SCOPE_AGENT);
            const float na = __hip_atomic_load(&neg_acc[i], __ATOMIC_RELAXED, __HIP_MEMORY_SCOPE_AGENT);
            const int ns = starts[i], ne = ends[i];
            const int lo = max(ns, 0), hi = min(ne, N - 1);
            const int inr = max(hi - lo + 1, 0);
            const bool dg = (i >= ns) && (i <= ne);
            const int pos_cnt = inr - (dg ? 1 : 0);
            const int neg_cnt = N - inr + (dg ? 1 : 0);
            if (pos_cnt > 0 && neg_cnt > 0) {
                total += pa / (float)max(pos_cnt, 1)
                       + LAM_NEG * na / (float)max(neg_cnt, 1);
                cnt++;
            }
        }
        for (int o = 32; o > 0; o >>= 1) {
            total += __shfl_down(total, o, 64);
            cnt   += __shfl_down(cnt, o, 64);
        }
        __shared__ float fin_ts[4];
        __shared__ int   fin_cs[4];
        if ((tid & 63) == 0) { fin_ts[tid >> 6] = total; fin_cs[tid >> 6] = cnt; }
        __syncthreads();
        if (tid == 0) {
            float T = fin_ts[0] + fin_ts[1] + fin_ts[2] + fin_ts[3];
            int   C = fin_cs[0] + fin_cs[1] + fin_cs[2] + fin_cs[3];
            out[0] = (C > 0) ? T / (float)C : 0.f;
        }
    }
}

extern "C" void kernel_launch(void* const* d_in, const int* in_sizes, int n_in,
                              void* d_out, int out_size, void* d_ws, size_t ws_size,
                              hipStream_t stream) {
    const float* cb     = (const float*)d_in[0];
    const int*   starts = (const int*)d_in[1];
    const int*   ends   = (const int*)d_in[2];
    const int*   max_ip = (const int*)d_in[3];
    float* out = (float*)d_out;

    const int N = in_sizes[1];
    const int d = in_sizes[0] / N;

    char* ws = (char*)d_ws;
    __hip_bfloat16* cb_bf = (__hip_bfloat16*)ws;
    size_t off = ((size_t)N * d * sizeof(__hip_bfloat16) + 255) & ~(size_t)255;
    float* sq       = (float*)(ws + off); off += (size_t)N * 4;
    float* inv_norm = (float*)(ws + off); off += (size_t)N * 4;
    float* pos_acc  = (float*)(ws + off); off += (size_t)N * 4;
    float* neg_acc  = (float*)(ws + off); off += (size_t)N * 4;
    unsigned* counter = (unsigned*)(ws + off); off += 256;

    // prep zeroes [pos_acc .. counter] = 2N floats + 1 u32
    prep_kernel<<<(N + 3) / 4, 256, 0, stream>>>(cb, cb_bf, sq, inv_norm,
                                                 (unsigned*)pos_acc, 2 * N + 1, N, d);

    const int nb = N / 128;
    const int nBlocks = nb * (nb + 1) / 2;   // upper-triangular tiles
    gram_loss_kernel<<<nBlocks, 256, 0, stream>>>(cb_bf, sq, inv_norm, starts, ends,
                                                  max_ip, pos_acc, neg_acc, counter,
                                                  out, N, d);
}

// Round 4
// 224.256 us; speedup vs baseline: 1.7450x; 1.7450x over previous
//
#include <hip/hip_runtime.h>
#include <hip/hip_bf16.h>
#include <stdint.h>

#define M_POS 0.5f
#define M_NEG 0.1f
#define LAM_NEG 1.0f

typedef __attribute__((ext_vector_type(8))) short short8;   // 8 bf16 = 4 VGPRs
typedef __attribute__((ext_vector_type(4))) float floatx4;  // MFMA accumulator

// ---------------- Kernel A: row sumsq, inv_norm, fp32 -> bf16 cast, zero accumulators ----
__global__ __launch_bounds__(256) void prep_kernel(
    const float* __restrict__ cb, __hip_bfloat16* __restrict__ cb_bf,
    float* __restrict__ sq, float* __restrict__ inv_norm,
    unsigned* __restrict__ zero_base, int zero_len,
    int N, int d)
{
    const int gi = blockIdx.x * 256 + threadIdx.x;
    if (gi < zero_len) zero_base[gi] = 0u;

    const int wave = threadIdx.x >> 6;
    const int lane = threadIdx.x & 63;
    const int row = blockIdx.x * 4 + wave;
    if (row >= N) return;
    const float* src = cb + (size_t)row * d;
    __hip_bfloat16* dst = cb_bf + (size_t)row * d;

    float s = 0.f;
    for (int c = lane * 4; c < d; c += 256) {
        float4 v = *(const float4*)(src + c);
        s += v.x * v.x + v.y * v.y + v.z * v.z + v.w * v.w;
        __hip_bfloat16 h[4];
        h[0] = __float2bfloat16(v.x);
        h[1] = __float2bfloat16(v.y);
        h[2] = __float2bfloat16(v.z);
        h[3] = __float2bfloat16(v.w);
        *(uint2*)(dst + c) = *(uint2*)h;
    }
    for (int o = 32; o > 0; o >>= 1) s += __shfl_down(s, o, 64);
    if (lane == 0) {
        sq[row] = s;
        inv_norm[row] = rsqrtf(s);
    }
}

// ---------------- Kernel B: fused symmetric Gram GEMM + loss epilogue ----------------
// Upper-triangular 128x128 tiles (by <= bx); off-diag tiles contribute each (i,j) to both
// row i and row j. XOR-swizzled LDS (0 bank conflicts, verified R2). ONE wave-uniform
// branch per tile: if no row/col in the wave's 64x64 window can have a positive pair
// (true for all off-diag tiles with 64-aligned groups), run a neg-only epilogue
// (no sqrt, no mask loads, no pos atomics). NO device-scope fences here (R3 regression).
__global__ __launch_bounds__(256) void gram_loss_kernel(
    const __hip_bfloat16* __restrict__ A,   // N x d bf16
    const float* __restrict__ sq, const float* __restrict__ inv_norm,
    const int* __restrict__ starts, const int* __restrict__ ends,
    const int* __restrict__ max_ip,
    float* __restrict__ pos_acc, float* __restrict__ neg_acc,
    int N, int d)
{
    const int M = min(N, max_ip[0] + 1);

    // triangular decode: blockIdx.x -> (by, bx), by <= bx
    const int t = blockIdx.x;
    int bx = (int)((sqrtf(8.f * (float)t + 1.f) - 1.f) * 0.5f);
    while ((bx + 1) * (bx + 2) / 2 <= t) bx++;
    while (bx * (bx + 1) / 2 > t) bx--;
    const int by = t - bx * (bx + 1) / 2;

    const int rowBase = by * 128;
    const int colBase = bx * 128;
    const bool isDiag = (by == bx);

    __shared__ __hip_bfloat16 ldsA[128 * 64];
    __shared__ __hip_bfloat16 ldsB[128 * 64];

    const int tid  = threadIdx.x;
    const int wave = tid >> 6;
    const int lane = tid & 63;
    const int wr = (wave >> 1) * 64;
    const int wc = (wave & 1) * 64;

    floatx4 acc[4][4];
#pragma unroll
    for (int a = 0; a < 4; ++a)
#pragma unroll
        for (int b = 0; b < 4; ++b) acc[a][b] = (floatx4){0.f, 0.f, 0.f, 0.f};

    const int ldRow = lane >> 3;
    const int dstCol = (lane & 7) * 8;
    const int srcCol = ((lane ^ ldRow) & 7) * 8;
    const int kTiles = d / 64;

    for (int kt = 0; kt < kTiles; ++kt) {
        __syncthreads();
        const int k0 = kt * 64;
#pragma unroll
        for (int q = 0; q < 4; ++q) {
            const int r = q * 32 + wave * 8 + ldRow;
            const __hip_bfloat16* ga = A + (size_t)(rowBase + r) * d + k0 + srcCol;
            const __hip_bfloat16* gb = A + (size_t)(colBase + r) * d + k0 + srcCol;
            __builtin_amdgcn_global_load_lds(
                (const __attribute__((address_space(1))) void*)ga,
                (__attribute__((address_space(3))) void*)(ldsA + r * 64 + dstCol), 16, 0, 0);
            __builtin_amdgcn_global_load_lds(
                (const __attribute__((address_space(1))) void*)gb,
                (__attribute__((address_space(3))) void*)(ldsB + r * 64 + dstCol), 16, 0, 0);
        }
        __syncthreads();

        const int rl = lane & 15;
        const int g  = lane >> 4;
#pragma unroll
        for (int ko = 0; ko < 2; ++ko) {
            const int kc = ko * 4 + g;
            short8 af[4], bf[4];
#pragma unroll
            for (int t4 = 0; t4 < 4; ++t4) {
                const int ra = wr + t4 * 16 + rl;
                const int rb = wc + t4 * 16 + rl;
                af[t4] = *(const short8*)(ldsA + ra * 64 + ((kc ^ (rl & 7)) * 8));
                bf[t4] = *(const short8*)(ldsB + rb * 64 + ((kc ^ (rl & 7)) * 8));
            }
#pragma unroll
            for (int rt = 0; rt < 4; ++rt)
#pragma unroll
                for (int ct = 0; ct < 4; ++ct)
                    acc[rt][ct] = __builtin_amdgcn_mfma_f32_16x16x32_bf16(
                        af[rt], bf[ct], acc[rt][ct], 0, 0, 0);
        }
    }

    // ---- epilogue ----
    const int rl = lane & 15;
    const int q  = lane >> 4;
    const int jlo = colBase + wc;         // wave's j-window [jlo, jlo+63]
    const int ilo = rowBase + wr;         // wave's i-window [ilo, ilo+63]

    int   jn[4];
    float jinv[4];
    bool  jvalid[4];
#pragma unroll
    for (int ct = 0; ct < 4; ++ct) {
        const int j = jlo + ct * 16 + rl;
        jn[ct]  = j;
        jinv[ct] = inv_norm[j];
        jvalid[ct] = (j < M);
    }

    // wave-uniform positive-pair possibility check: lane L checks row ilo+L and col jlo+L
    bool posLane = false;
    {
        const int ri = ilo + lane;
        if (ri < M) posLane |= (ends[ri] >= jlo) && (starts[ri] <= jlo + 63);
        if (!isDiag) {
            const int cj = jlo + lane;
            if (cj < M) posLane |= (ends[cj] >= ilo) && (starts[cj] <= ilo + 63);
        }
    }
    const bool fullPath = (__ballot(posLane) != 0ULL);

    float posc[4] = {0.f, 0.f, 0.f, 0.f};
    float negc[4] = {0.f, 0.f, 0.f, 0.f};

    if (fullPath) {
        int   jns[4], jne[4];
        float jsq[4];
#pragma unroll
        for (int ct = 0; ct < 4; ++ct) {
            jsq[ct] = sq[jn[ct]];
            jns[ct] = jvalid[ct] ? starts[jn[ct]] : 0;
            jne[ct] = jvalid[ct] ? ends[jn[ct]]   : -1;
        }
#pragma unroll
        for (int rt = 0; rt < 4; ++rt) {
            const int ibase = rowBase + wr + rt * 16 + q * 4;
#pragma unroll
            for (int reg = 0; reg < 4; ++reg) {
                const int i = ibase + reg;
                const bool rowValid = (i < M);
                const int ns = rowValid ? starts[i] : 0;
                const int ne = rowValid ? ends[i]   : -1;
                const float iinv = inv_norm[i];
                const float isq  = sq[i];
                float posp = 0.f, negp = 0.f;
#pragma unroll
                for (int ct = 0; ct < 4; ++ct) {
                    const float dot = acc[rt][ct][reg];
                    const int j = jn[ct];
                    float cosv = dot * iinv * jinv[ct];
                    cosv = fminf(fmaxf(cosv, -1.f), 1.f);
                    float tn = fmaxf(fabsf(cosv) - M_NEG, 0.f);
                    const float nterm = tn * tn;
                    const float d2 = fmaxf(isq + jsq[ct] - 2.f * dot, 0.f);
                    float tp = fmaxf(sqrtf(d2) - M_POS, 0.f);
                    const float pterm = tp * tp;
                    const bool dg = (j == i);
                    if (rowValid) {
                        const bool in_r = (j >= ns) && (j <= ne);
                        if (in_r && !dg) posp += pterm;
                        if (!in_r || dg) negp += nterm;
                    }
                    if (!isDiag && jvalid[ct]) {
                        const bool in_c = (i >= jns[ct]) && (i <= jne[ct]);
                        if (in_c && !dg) posc[ct] += pterm;
                        if (!in_c || dg) negc[ct] += nterm;
                    }
                }
#pragma unroll
                for (int m = 1; m < 16; m <<= 1) {
                    posp += __shfl_xor(posp, m, 64);
                    negp += __shfl_xor(negp, m, 64);
                }
                if (rowValid && rl == 0) {
                    atomicAdd(&pos_acc[i], posp);
                    atomicAdd(&neg_acc[i], negp);
                }
            }
        }
        if (!isDiag) {
#pragma unroll
            for (int ct = 0; ct < 4; ++ct) {
                posc[ct] += __shfl_xor(posc[ct], 16, 64);
                posc[ct] += __shfl_xor(posc[ct], 32, 64);
                negc[ct] += __shfl_xor(negc[ct], 16, 64);
                negc[ct] += __shfl_xor(negc[ct], 32, 64);
            }
            if (q == 0) {
#pragma unroll
                for (int ct = 0; ct < 4; ++ct) {
                    if (jvalid[ct]) {
                        atomicAdd(&pos_acc[jn[ct]], posc[ct]);
                        atomicAdd(&neg_acc[jn[ct]], negc[ct]);
                    }
                }
            }
        }
    } else {
        // fast path: no positive pair possible in this wave's window →
        // every element is a negative for both its row and its column.
        // No sqrt, no mask loads, no pos atomics.
#pragma unroll
        for (int rt = 0; rt < 4; ++rt) {
            const int ibase = rowBase + wr + rt * 16 + q * 4;
#pragma unroll
            for (int reg = 0; reg < 4; ++reg) {
                const int i = ibase + reg;
                const float iinv = inv_norm[i];
                float negp = 0.f;
#pragma unroll
                for (int ct = 0; ct < 4; ++ct) {
                    const float dot = acc[rt][ct][reg];
                    float cosv = dot * iinv * jinv[ct];
                    cosv = fminf(fmaxf(cosv, -1.f), 1.f);
                    float tn = fmaxf(fabsf(cosv) - M_NEG, 0.f);
                    const float nterm = tn * tn;
                    negp += nterm;
                    negc[ct] += nterm;   // col side (off-diag only; fast path never diag w/ groups in-window)
                }
#pragma unroll
                for (int m = 1; m < 16; m <<= 1)
                    negp += __shfl_xor(negp, m, 64);
                if ((i < M) && rl == 0)
                    atomicAdd(&neg_acc[i], negp);
            }
        }
        if (!isDiag) {
#pragma unroll
            for (int ct = 0; ct < 4; ++ct) {
                negc[ct] += __shfl_xor(negc[ct], 16, 64);
                negc[ct] += __shfl_xor(negc[ct], 32, 64);
            }
            if (q == 0) {
#pragma unroll
                for (int ct = 0; ct < 4; ++ct)
                    if (jvalid[ct])
                        atomicAdd(&neg_acc[jn[ct]], negc[ct]);
            }
        }
    }
}

// ---------------- Kernel C: per-row normalize + global mean ----------------
__global__ __launch_bounds__(1024) void finalize_kernel(
    const float* __restrict__ pos_acc, const float* __restrict__ neg_acc,
    const int* __restrict__ starts, const int* __restrict__ ends,
    const int* __restrict__ max_ip, int N, float* __restrict__ out)
{
    const int M = min(N, max_ip[0] + 1);
    const int t = threadIdx.x;
    float total = 0.f;
    int cnt = 0;
    for (int i = t; i < M; i += blockDim.x) {
        const int ns = starts[i], ne = ends[i];
        const int lo = max(ns, 0), hi = min(ne, N - 1);
        const int inr = max(hi - lo + 1, 0);
        const bool dg = (i >= ns) && (i <= ne);
        const int pos_cnt = inr - (dg ? 1 : 0);
        const int neg_cnt = N - inr + (dg ? 1 : 0);
        if (pos_cnt > 0 && neg_cnt > 0) {
            total += pos_acc[i] / (float)max(pos_cnt, 1)
                   + LAM_NEG * neg_acc[i] / (float)max(neg_cnt, 1);
            cnt++;
        }
    }
    for (int o = 32; o > 0; o >>= 1) {
        total += __shfl_down(total, o, 64);
        cnt   += __shfl_down(cnt, o, 64);
    }
    __shared__ float ts[16];
    __shared__ int   cs[16];
    const int w = t >> 6;
    if ((t & 63) == 0) { ts[w] = total; cs[w] = cnt; }
    __syncthreads();
    if (t == 0) {
        float T = 0.f; int C = 0;
        const int nw = blockDim.x >> 6;
        for (int i = 0; i < nw; ++i) { T += ts[i]; C += cs[i]; }
        out[0] = (C > 0) ? T / (float)C : 0.f;
    }
}

extern "C" void kernel_launch(void* const* d_in, const int* in_sizes, int n_in,
                              void* d_out, int out_size, void* d_ws, size_t ws_size,
                              hipStream_t stream) {
    const float* cb     = (const float*)d_in[0];
    const int*   starts = (const int*)d_in[1];
    const int*   ends   = (const int*)d_in[2];
    const int*   max_ip = (const int*)d_in[3];
    float* out = (float*)d_out;

    const int N = in_sizes[1];
    const int d = in_sizes[0] / N;

    char* ws = (char*)d_ws;
    __hip_bfloat16* cb_bf = (__hip_bfloat16*)ws;
    size_t off = ((size_t)N * d * sizeof(__hip_bfloat16) + 255) & ~(size_t)255;
    float* sq       = (float*)(ws + off); off += (size_t)N * 4;
    float* inv_norm = (float*)(ws + off); off += (size_t)N * 4;
    float* pos_acc  = (float*)(ws + off); off += (size_t)N * 4;
    float* neg_acc  = (float*)(ws + off); off += (size_t)N * 4;

    // prep zeroes pos_acc/neg_acc (2N u32)
    prep_kernel<<<(N + 3) / 4, 256, 0, stream>>>(cb, cb_bf, sq, inv_norm,
                                                 (unsigned*)pos_acc, 2 * N, N, d);

    const int nb = N / 128;
    const int nBlocks = nb * (nb + 1) / 2;   // upper-triangular tiles
    gram_loss_kernel<<<nBlocks, 256, 0, stream>>>(cb_bf, sq, inv_norm, starts, ends,
                                                  max_ip, pos_acc, neg_acc, N, d);

    finalize_kernel<<<1, 1024, 0, stream>>>(pos_acc, neg_acc, starts, ends, max_ip, N, out);
}

// Round 5
// 213.273 us; speedup vs baseline: 1.8349x; 1.0515x over previous
//
#include <hip/hip_runtime.h>
#include <hip/hip_bf16.h>
#include <stdint.h>

#define M_POS 0.5f
#define M_NEG 0.1f
#define LAM_NEG 1.0f

typedef __attribute__((ext_vector_type(4))) float floatx4;  // MFMA accumulator
using f8x8 = long;   // 8 fp8 bytes = 2 VGPRs (i64 MFMA operand)

// ---------------- Kernel A: row sumsq, inv_norm, fp32 -> fp8(e4m3) quantize, zero accs ----
// One block (4 waves) per row for max wave-parallelism (R2's 4-rows/block was slower).
__global__ __launch_bounds__(256) void prep_kernel(
    const float* __restrict__ cb, unsigned char* __restrict__ cb_q,
    float* __restrict__ sq, float* __restrict__ inv_norm,
    unsigned* __restrict__ zero_base, int zero_len,
    int N, int d)
{
    const int gi = blockIdx.x * 256 + threadIdx.x;
    if (gi < zero_len) zero_base[gi] = 0u;

    const int row = blockIdx.x;
    const float* src = cb + (size_t)row * d;
    unsigned char* dst = cb_q + (size_t)row * d;
    const int t = threadIdx.x;

    float s = 0.f;
    for (int c = t * 4; c < d; c += 1024) {
        float4 v = *(const float4*)(src + c);
        s += v.x * v.x + v.y * v.y + v.z * v.z + v.w * v.w;
        int pk = __builtin_amdgcn_cvt_pk_fp8_f32(v.x, v.y, 0, false);   // bytes 0,1
        pk     = __builtin_amdgcn_cvt_pk_fp8_f32(v.z, v.w, pk, true);   // bytes 2,3
        *(int*)(dst + c) = pk;
    }
    for (int o = 32; o > 0; o >>= 1) s += __shfl_down(s, o, 64);
    __shared__ float wsum[4];
    if ((t & 63) == 0) wsum[t >> 6] = s;
    __syncthreads();
    if (t == 0) {
        float tot = wsum[0] + wsum[1] + wsum[2] + wsum[3];
        sq[row] = tot;
        inv_norm[row] = rsqrtf(tot);
    }
}

// ---------------- Kernel B: fused symmetric fp8 Gram GEMM + loss epilogue ----------------
// Upper-triangular 128x128 tiles (by <= bx). fp8 e4m3 inputs, fp32 accumulate via
// v_mfma_f32_16x16x32_fp8_fp8 (same loop shape as bf16, half the LDS/fetch bytes).
// LDS rows are 64 B; 16B chunk q of row R stores logical chunk q^((R>>1)&3) so the
// fragment ds_read_b64 lands exactly 4 touches/bank (the b64 floor). Wave-uniform
// pos-skip branch as in R4. No device-scope fences (R3 regression).
__global__ __launch_bounds__(256) void gram_loss_kernel(
    const unsigned char* __restrict__ A,   // N x d fp8
    const float* __restrict__ sq, const float* __restrict__ inv_norm,
    const int* __restrict__ starts, const int* __restrict__ ends,
    const int* __restrict__ max_ip,
    float* __restrict__ pos_acc, float* __restrict__ neg_acc,
    int N, int d)
{
    const int M = min(N, max_ip[0] + 1);

    // triangular decode: blockIdx.x -> (by, bx), by <= bx
    const int t = blockIdx.x;
    int bx = (int)((sqrtf(8.f * (float)t + 1.f) - 1.f) * 0.5f);
    while ((bx + 1) * (bx + 2) / 2 <= t) bx++;
    while (bx * (bx + 1) / 2 > t) bx--;
    const int by = t - bx * (bx + 1) / 2;

    const int rowBase = by * 128;
    const int colBase = bx * 128;
    const bool isDiag = (by == bx);

    __shared__ alignas(16) unsigned char ldsA[128 * 64];
    __shared__ alignas(16) unsigned char ldsB[128 * 64];

    const int tid  = threadIdx.x;
    const int wave = tid >> 6;
    const int lane = tid & 63;
    const int wr = (wave >> 1) * 64;
    const int wc = (wave & 1) * 64;

    floatx4 acc[4][4];
#pragma unroll
    for (int a = 0; a < 4; ++a)
#pragma unroll
        for (int b = 0; b < 4; ++b) acc[a][b] = (floatx4){0.f, 0.f, 0.f, 0.f};

    // staging: 16 rows x 4 chunks per wave-issue; dst = base + lane*16 (lane-linear).
    const int sR = lane >> 2;                       // local row 0..15
    const int sQ = lane & 3;                        // 16B chunk 0..3
    const int kTiles = d / 64;

    // fragment-read constants
    const int rl = lane & 15;
    const int g  = lane >> 4;       // 0..3
    const int rowx = (rl >> 1) & 3; // row-dependent chunk xor
    const int ghalf = g >> 1;
    const int godd  = (g & 1) * 8;

    for (int kt = 0; kt < kTiles; ++kt) {
        __syncthreads();
        const int k0 = kt * 64;
#pragma unroll
        for (int h = 0; h < 2; ++h) {
            const int r = wave * 32 + h * 16 + sR;              // tile row 0..127
            const int srcQ = sQ ^ ((r >> 1) & 3);
            const unsigned char* ga = A + (size_t)(rowBase + r) * d + k0 + srcQ * 16;
            const unsigned char* gb = A + (size_t)(colBase + r) * d + k0 + srcQ * 16;
            __builtin_amdgcn_global_load_lds(
                (const __attribute__((address_space(1))) void*)ga,
                (__attribute__((address_space(3))) void*)(ldsA + r * 64 + sQ * 16), 16, 0, 0);
            __builtin_amdgcn_global_load_lds(
                (const __attribute__((address_space(1))) void*)gb,
                (__attribute__((address_space(3))) void*)(ldsB + r * 64 + sQ * 16), 16, 0, 0);
        }
        __syncthreads();

#pragma unroll
        for (int ko = 0; ko < 2; ++ko) {
            const int phys16 = ((ko * 2 + ghalf) ^ rowx);
            const int koff = phys16 * 16 + godd;
            f8x8 af[4], bf[4];
#pragma unroll
            for (int t4 = 0; t4 < 4; ++t4) {
                const int ra = wr + t4 * 16 + rl;
                const int rb = wc + t4 * 16 + rl;
                af[t4] = *(const f8x8*)(ldsA + ra * 64 + koff);
                bf[t4] = *(const f8x8*)(ldsB + rb * 64 + koff);
            }
#pragma unroll
            for (int rt = 0; rt < 4; ++rt)
#pragma unroll
                for (int ct = 0; ct < 4; ++ct)
                    acc[rt][ct] = __builtin_amdgcn_mfma_f32_16x16x32_fp8_fp8(
                        af[rt], bf[ct], acc[rt][ct], 0, 0, 0);
        }
    }

    // ---- epilogue ----
    const int q  = lane >> 4;
    const int jlo = colBase + wc;
    const int ilo = rowBase + wr;

    int   jn[4];
    float jinv[4];
    bool  jvalid[4];
#pragma unroll
    for (int ct = 0; ct < 4; ++ct) {
        const int j = jlo + ct * 16 + rl;
        jn[ct]  = j;
        jinv[ct] = inv_norm[j];
        jvalid[ct] = (j < M);
    }

    // wave-uniform positive-pair possibility check
    bool posLane = false;
    {
        const int ri = ilo + lane;
        if (ri < M) posLane |= (ends[ri] >= jlo) && (starts[ri] <= jlo + 63);
        if (!isDiag) {
            const int cj = jlo + lane;
            if (cj < M) posLane |= (ends[cj] >= ilo) && (starts[cj] <= ilo + 63);
        }
    }
    const bool fullPath = (__ballot(posLane) != 0ULL);

    float posc[4] = {0.f, 0.f, 0.f, 0.f};
    float negc[4] = {0.f, 0.f, 0.f, 0.f};

    if (fullPath) {
        int   jns[4], jne[4];
        float jsq[4];
#pragma unroll
        for (int ct = 0; ct < 4; ++ct) {
            jsq[ct] = sq[jn[ct]];
            jns[ct] = jvalid[ct] ? starts[jn[ct]] : 0;
            jne[ct] = jvalid[ct] ? ends[jn[ct]]   : -1;
        }
#pragma unroll
        for (int rt = 0; rt < 4; ++rt) {
            const int ibase = rowBase + wr + rt * 16 + q * 4;
#pragma unroll
            for (int reg = 0; reg < 4; ++reg) {
                const int i = ibase + reg;
                const bool rowValid = (i < M);
                const int ns = rowValid ? starts[i] : 0;
                const int ne = rowValid ? ends[i]   : -1;
                const float iinv = inv_norm[i];
                const float isq  = sq[i];
                float posp = 0.f, negp = 0.f;
#pragma unroll
                for (int ct = 0; ct < 4; ++ct) {
                    const float dot = acc[rt][ct][reg];
                    const int j = jn[ct];
                    float cosv = dot * iinv * jinv[ct];
                    cosv = fminf(fmaxf(cosv, -1.f), 1.f);
                    float tn = fmaxf(fabsf(cosv) - M_NEG, 0.f);
                    const float nterm = tn * tn;
                    const float d2 = fmaxf(isq + jsq[ct] - 2.f * dot, 0.f);
                    float tp = fmaxf(sqrtf(d2) - M_POS, 0.f);
                    const float pterm = tp * tp;
                    const bool dg = (j == i);
                    if (rowValid) {
                        const bool in_r = (j >= ns) && (j <= ne);
                        if (in_r && !dg) posp += pterm;
                        if (!in_r || dg) negp += nterm;
                    }
                    if (!isDiag && jvalid[ct]) {
                        const bool in_c = (i >= jns[ct]) && (i <= jne[ct]);
                        if (in_c && !dg) posc[ct] += pterm;
                        if (!in_c || dg) negc[ct] += nterm;
                    }
                }
#pragma unroll
                for (int m = 1; m < 16; m <<= 1) {
                    posp += __shfl_xor(posp, m, 64);
                    negp += __shfl_xor(negp, m, 64);
                }
                if (rowValid && rl == 0) {
                    atomicAdd(&pos_acc[i], posp);
                    atomicAdd(&neg_acc[i], negp);
                }
            }
        }
        if (!isDiag) {
#pragma unroll
            for (int ct = 0; ct < 4; ++ct) {
                posc[ct] += __shfl_xor(posc[ct], 16, 64);
                posc[ct] += __shfl_xor(posc[ct], 32, 64);
                negc[ct] += __shfl_xor(negc[ct], 16, 64);
                negc[ct] += __shfl_xor(negc[ct], 32, 64);
            }
            if (q == 0) {
#pragma unroll
                for (int ct = 0; ct < 4; ++ct) {
                    if (jvalid[ct]) {
                        atomicAdd(&pos_acc[jn[ct]], posc[ct]);
                        atomicAdd(&neg_acc[jn[ct]], negc[ct]);
                    }
                }
            }
        }
    } else {
        // fast path: every element is a negative for both its row and its column
#pragma unroll
        for (int rt = 0; rt < 4; ++rt) {
            const int ibase = rowBase + wr + rt * 16 + q * 4;
#pragma unroll
            for (int reg = 0; reg < 4; ++reg) {
                const int i = ibase + reg;
                const float iinv = inv_norm[i];
                float negp = 0.f;
#pragma unroll
                for (int ct = 0; ct < 4; ++ct) {
                    const float dot = acc[rt][ct][reg];
                    float cosv = dot * iinv * jinv[ct];
                    cosv = fminf(fmaxf(cosv, -1.f), 1.f);
                    float tn = fmaxf(fabsf(cosv) - M_NEG, 0.f);
                    const float nterm = tn * tn;
                    negp += nterm;
                    negc[ct] += nterm;
                }
#pragma unroll
                for (int m = 1; m < 16; m <<= 1)
                    negp += __shfl_xor(negp, m, 64);
                if ((i < M) && rl == 0)
                    atomicAdd(&neg_acc[i], negp);
            }
        }
        if (!isDiag) {
#pragma unroll
            for (int ct = 0; ct < 4; ++ct) {
                negc[ct] += __shfl_xor(negc[ct], 16, 64);
                negc[ct] += __shfl_xor(negc[ct], 32, 64);
            }
            if (q == 0) {
#pragma unroll
                for (int ct = 0; ct < 4; ++ct)
                    if (jvalid[ct])
                        atomicAdd(&neg_acc[jn[ct]], negc[ct]);
            }
        }
    }
}

// ---------------- Kernel C: per-row normalize + global mean ----------------
__global__ __launch_bounds__(1024) void finalize_kernel(
    const float* __restrict__ pos_acc, const float* __restrict__ neg_acc,
    const int* __restrict__ starts, const int* __restrict__ ends,
    const int* __restrict__ max_ip, int N, float* __restrict__ out)
{
    const int M = min(N, max_ip[0] + 1);
    const int t = threadIdx.x;
    float total = 0.f;
    int cnt = 0;
    for (int i = t; i < M; i += blockDim.x) {
        const int ns = starts[i], ne = ends[i];
        const int lo = max(ns, 0), hi = min(ne, N - 1);
        const int inr = max(hi - lo + 1, 0);
        const bool dg = (i >= ns) && (i <= ne);
        const int pos_cnt = inr - (dg ? 1 : 0);
        const int neg_cnt = N - inr + (dg ? 1 : 0);
        if (pos_cnt > 0 && neg_cnt > 0) {
            total += pos_acc[i] / (float)max(pos_cnt, 1)
                   + LAM_NEG * neg_acc[i] / (float)max(neg_cnt, 1);
            cnt++;
        }
    }
    for (int o = 32; o > 0; o >>= 1) {
        total += __shfl_down(total, o, 64);
        cnt   += __shfl_down(cnt, o, 64);
    }
    __shared__ float ts[16];
    __shared__ int   cs[16];
    const int w = t >> 6;
    if ((t & 63) == 0) { ts[w] = total; cs[w] = cnt; }
    __syncthreads();
    if (t == 0) {
        float T = 0.f; int C = 0;
        const int nw = blockDim.x >> 6;
        for (int i = 0; i < nw; ++i) { T += ts[i]; C += cs[i]; }
        out[0] = (C > 0) ? T / (float)C : 0.f;
    }
}

extern "C" void kernel_launch(void* const* d_in, const int* in_sizes, int n_in,
                              void* d_out, int out_size, void* d_ws, size_t ws_size,
                              hipStream_t stream) {
    const float* cb     = (const float*)d_in[0];
    const int*   starts = (const int*)d_in[1];
    const int*   ends   = (const int*)d_in[2];
    const int*   max_ip = (const int*)d_in[3];
    float* out = (float*)d_out;

    const int N = in_sizes[1];
    const int d = in_sizes[0] / N;

    char* ws = (char*)d_ws;
    unsigned char* cb_q = (unsigned char*)ws;
    size_t off = ((size_t)N * d + 255) & ~(size_t)255;
    float* sq       = (float*)(ws + off); off += (size_t)N * 4;
    float* inv_norm = (float*)(ws + off); off += (size_t)N * 4;
    float* pos_acc  = (float*)(ws + off); off += (size_t)N * 4;
    float* neg_acc  = (float*)(ws + off); off += (size_t)N * 4;

    // prep zeroes pos_acc/neg_acc (2N u32)
    prep_kernel<<<N, 256, 0, stream>>>(cb, cb_q, sq, inv_norm,
                                       (unsigned*)pos_acc, 2 * N, N, d);

    const int nb = N / 128;
    const int nBlocks = nb * (nb + 1) / 2;   // upper-triangular tiles
    gram_loss_kernel<<<nBlocks, 256, 0, stream>>>(cb_q, sq, inv_norm, starts, ends,
                                                  max_ip, pos_acc, neg_acc, N, d);

    finalize_kernel<<<1, 1024, 0, stream>>>(pos_acc, neg_acc, starts, ends, max_ip, N, out);
}